// Round 1
// baseline (3938.097 us; speedup 1.0000x reference)
//
#include <hip/hip_runtime.h>
#include <cmath>

// Problem constants
#define V_   50280
#define DM_  768
#define NL_  4
#define DS_  16
#define DC_  4
#define DTR_ 48
#define ROH_ 512
#define RH2_ 256
#define DI_  1536
#define B_   2
#define L_   128
#define T_   256   // B_*L_

__device__ __forceinline__ float silu_f(float x) { return x / (1.f + expf(-x)); }

// ---------------------------------------------------------------------------
// gather: x[t,:] = embed[ids[t],:]
// ---------------------------------------------------------------------------
__global__ __launch_bounds__(256) void gather_kernel(
    const int* __restrict__ ids, const float* __restrict__ embed,
    float* __restrict__ x)
{
    int t = blockIdx.x, tid = threadIdx.x;
    int id = ids[t];
#pragma unroll
    for (int i = 0; i < 3; i++)
        x[t * 768 + i * 256 + tid] = embed[(size_t)id * 768 + i * 256 + tid];
}

// ---------------------------------------------------------------------------
// rmsnorm over DM=768, one block per token, 256 threads
// ---------------------------------------------------------------------------
__global__ __launch_bounds__(256) void rmsnorm_kernel(
    const float* __restrict__ x, const float* __restrict__ w,
    float* __restrict__ out)
{
    int t = blockIdx.x;
    int tid = threadIdx.x;
    float v0 = x[t * 768 + tid];
    float v1 = x[t * 768 + 256 + tid];
    float v2 = x[t * 768 + 512 + tid];
    float s = v0 * v0 + v1 * v1 + v2 * v2;
#pragma unroll
    for (int off = 32; off >= 1; off >>= 1) s += __shfl_xor(s, off, 64);
    __shared__ float red[4];
    int wid = tid >> 6, lane = tid & 63;
    if (lane == 0) red[wid] = s;
    __syncthreads();
    s = red[0] + red[1] + red[2] + red[3];
    float scale = rsqrtf(s * (1.f / 768.f) + 1e-5f);
    out[t * 768 + tid]       = v0 * scale * w[tid];
    out[t * 768 + 256 + tid] = v1 * scale * w[256 + tid];
    out[t * 768 + 512 + tid] = v2 * scale * w[512 + tid];
}

// ---------------------------------------------------------------------------
// generic fp32 GEMM, 64x64 tile, TK=16, 256 threads, 4x4 per thread
// BT: 0 -> Bw is K x N (row-major, ldb = row stride)
//     1 -> Bw is N x K (row-major, ldb = row stride), i.e. C = A * Bw^T
// EPI: 0 none, 1 +bias, 2 relu(+bias), 3 softplus(+bias), 4 C += v
// ---------------------------------------------------------------------------
template <int BT, int EPI>
__global__ __launch_bounds__(256) void gemm64_kernel(
    const float* __restrict__ A, const float* __restrict__ Bw,
    const float* __restrict__ bias, float* __restrict__ C,
    int M, int N, int K, int lda, int ldb, int ldc)
{
    __shared__ float As[16][68];
    __shared__ float Bs[16][68];
    const int tid = threadIdx.x;
    const int bm = blockIdx.y * 64;
    const int bn = blockIdx.x * 64;
    const int tx = tid & 15, ty = tid >> 4;
    float acc[4][4] = {};
    for (int k0 = 0; k0 < K; k0 += 16) {
        {   // A tile: 64 rows x 16 k
            int m = tid >> 2;
            int kb = (tid & 3) << 2;
            bool mok = (bm + m) < M;
            const float* ap = A + (size_t)(bm + m) * lda + k0 + kb;
#pragma unroll
            for (int i = 0; i < 4; i++)
                As[kb + i][m] = (mok && (k0 + kb + i) < K) ? ap[i] : 0.f;
        }
        if (BT) {
            int n = tid >> 2;
            int kb = (tid & 3) << 2;
            bool nok = (bn + n) < N;
            const float* bp = Bw + (size_t)(bn + n) * ldb + k0 + kb;
#pragma unroll
            for (int i = 0; i < 4; i++)
                Bs[kb + i][n] = (nok && (k0 + kb + i) < K) ? bp[i] : 0.f;
        } else {
            int kk = tid >> 4;
            int nb = (tid & 15) << 2;
            bool kok = (k0 + kk) < K;
            const float* bp = Bw + (size_t)(k0 + kk) * ldb + bn + nb;
#pragma unroll
            for (int i = 0; i < 4; i++)
                Bs[kk][nb + i] = (kok && (bn + nb + i) < N) ? bp[i] : 0.f;
        }
        __syncthreads();
#pragma unroll
        for (int k = 0; k < 16; k++) {
            float a[4], b[4];
#pragma unroll
            for (int i = 0; i < 4; i++) a[i] = As[k][ty * 4 + i];
#pragma unroll
            for (int j = 0; j < 4; j++) b[j] = Bs[k][tx * 4 + j];
#pragma unroll
            for (int i = 0; i < 4; i++)
#pragma unroll
                for (int j = 0; j < 4; j++)
                    acc[i][j] = fmaf(a[i], b[j], acc[i][j]);
        }
        __syncthreads();
    }
#pragma unroll
    for (int i = 0; i < 4; i++) {
        int m = bm + ty * 4 + i;
        if (m >= M) continue;
#pragma unroll
        for (int j = 0; j < 4; j++) {
            int n = bn + tx * 4 + j;
            if (n >= N) continue;
            float v = acc[i][j];
            if (EPI >= 1 && EPI <= 3) v += bias[n];
            if (EPI == 2) v = fmaxf(v, 0.f);
            if (EPI == 3) v = fmaxf(v, 0.f) + log1pf(expf(-fabsf(v)));
            float* cp = &C[(size_t)m * ldc + n];
            if (EPI == 4) v += *cp;
            *cp = v;
        }
    }
}

// ---------------------------------------------------------------------------
// fp32 GEMM, 128x128 tile, TK=8, 256 threads, 8x8 per thread (large-N GEMMs)
// ---------------------------------------------------------------------------
template <int BT, int EPI>
__global__ __launch_bounds__(256) void gemm128_kernel(
    const float* __restrict__ A, const float* __restrict__ Bw,
    const float* __restrict__ bias, float* __restrict__ C,
    int M, int N, int K, int lda, int ldb, int ldc)
{
    __shared__ float As[8][132];
    __shared__ float Bs[8][132];
    const int tid = threadIdx.x;
    const int bm = blockIdx.y * 128;
    const int bn = blockIdx.x * 128;
    const int tx = tid & 15, ty = tid >> 4;
    float acc[8][8] = {};
    for (int k0 = 0; k0 < K; k0 += 8) {
        {   // A tile: 128 rows x 8 k
            int m = tid >> 1;
            int kb = (tid & 1) << 2;
            bool mok = (bm + m) < M;
            const float* ap = A + (size_t)(bm + m) * lda + k0 + kb;
#pragma unroll
            for (int i = 0; i < 4; i++)
                As[kb + i][m] = (mok && (k0 + kb + i) < K) ? ap[i] : 0.f;
        }
        if (BT) {
            int n = tid >> 1;
            int kb = (tid & 1) << 2;
            bool nok = (bn + n) < N;
            const float* bp = Bw + (size_t)(bn + n) * ldb + k0 + kb;
#pragma unroll
            for (int i = 0; i < 4; i++)
                Bs[kb + i][n] = (nok && (k0 + kb + i) < K) ? bp[i] : 0.f;
        } else {
            int kk = tid >> 5;
            int nb = (tid & 31) << 2;
            bool kok = (k0 + kk) < K;
            const float* bp = Bw + (size_t)(k0 + kk) * ldb + bn + nb;
#pragma unroll
            for (int i = 0; i < 4; i++)
                Bs[kk][nb + i] = (kok && (bn + nb + i) < N) ? bp[i] : 0.f;
        }
        __syncthreads();
#pragma unroll
        for (int k = 0; k < 8; k++) {
            float a[8], b[8];
#pragma unroll
            for (int i = 0; i < 8; i++) a[i] = As[k][ty * 8 + i];
#pragma unroll
            for (int j = 0; j < 8; j++) b[j] = Bs[k][tx * 8 + j];
#pragma unroll
            for (int i = 0; i < 8; i++)
#pragma unroll
                for (int j = 0; j < 8; j++)
                    acc[i][j] = fmaf(a[i], b[j], acc[i][j]);
        }
        __syncthreads();
    }
#pragma unroll
    for (int i = 0; i < 8; i++) {
        int m = bm + ty * 8 + i;
        if (m >= M) continue;
#pragma unroll
        for (int j = 0; j < 8; j++) {
            int n = bn + tx * 8 + j;
            if (n >= N) continue;
            float v = acc[i][j];
            if (EPI >= 1 && EPI <= 3) v += bias[n];
            if (EPI == 2) v = fmaxf(v, 0.f);
            C[(size_t)m * ldc + n] = v;
        }
    }
}

// ---------------------------------------------------------------------------
// causal depthwise conv (DC=4) + silu. One block per token row.
// xz row stride 3072; channels = first 1536 columns.
// ---------------------------------------------------------------------------
__global__ __launch_bounds__(256) void conv_silu_kernel(
    const float* __restrict__ xz, const float* __restrict__ cw,
    const float* __restrict__ cb, float* __restrict__ xconv)
{
    int row = blockIdx.x;       // b*128 + t
    int t = row & 127;
    int tid = threadIdx.x;
    for (int c = tid; c < 1536; c += 256) {
        float acc = cb[c];
#pragma unroll
        for (int k = 0; k < 4; k++) {
            int tt = t - 3 + k;
            if (tt >= 0) acc += cw[c * 4 + k] * xz[(size_t)(row - 3 + k) * 3072 + c];
        }
        xconv[(size_t)row * 1536 + c] = silu_f(acc);
    }
}

// ---------------------------------------------------------------------------
// selective scan: one lane per (b, di, ds); 16-lane shuffle reduce for y.
// Writes hidden states (layer slab, layout (B,L,DI,DS)) and
// y = (sum_ds h*C + D*u) * silu(z).
// grid = 192 blocks x 256
// ---------------------------------------------------------------------------
__global__ __launch_bounds__(256) void scan_kernel(
    const float* __restrict__ delta, const float* __restrict__ xconv,
    const float* __restrict__ dbc, const float* __restrict__ xz,
    const float* __restrict__ A_log, const float* __restrict__ Dp,
    float* __restrict__ hid_l, float* __restrict__ yout)
{
    int gtid = blockIdx.x * 256 + threadIdx.x;  // 0..49151 = B*DI*DS
    int ds = gtid & 15;
    int di = (gtid >> 4) % 1536;
    int b  = gtid / 24576;
    float a = -expf(A_log[di * 16 + ds]);
    float dval = Dp[di];
    float h = 0.f;
    for (int t = 0; t < 128; t++) {
        int row = b * 128 + t;
        float dlt = delta[row * 1536 + di];
        float u   = xconv[row * 1536 + di];
        float Bv  = dbc[row * 80 + 48 + ds];
        float Cv  = dbc[row * 80 + 64 + ds];
        h = expf(dlt * a) * h + dlt * Bv * u;
        hid_l[(size_t)row * 24576 + di * 16 + ds] = h;
        float p = h * Cv;
        p += __shfl_xor(p, 1, 64);
        p += __shfl_xor(p, 2, 64);
        p += __shfl_xor(p, 4, 64);
        p += __shfl_xor(p, 8, 64);
        if (ds == 0) {
            float z = xz[(size_t)row * 3072 + 1536 + di];
            yout[row * 1536 + di] = (p + dval * u) * silu_f(z);
        }
    }
}

// ---------------------------------------------------------------------------
// readout GEMM1 split-K: feat(256 x 98304) @ ro_w1(98304 x 512).
// feat is read directly from hidden (never materialized): global k =
// l*24576 + inner, and hidden row (l*2+b)*128+t holds 24576 contiguous
// floats. K-chunk = 3072 (8 chunks per layer slab -> chunk stays in one l).
// grid: x = N/128 = 4, y = M/128 = 2, z = chunk = 32
// ---------------------------------------------------------------------------
__global__ __launch_bounds__(256) void feat_splitk_kernel(
    const float* __restrict__ hid, const float* __restrict__ W1,
    float* __restrict__ partial)
{
    __shared__ float As[8][132];
    __shared__ float Bs[8][132];
    const int tid = threadIdx.x;
    const int bn = blockIdx.x * 128;
    const int bm = blockIdx.y * 128;
    const int chunk = blockIdx.z;
    const int l = chunk >> 3;
    const int inner0 = (chunk & 7) * 3072;
    const size_t kg0 = (size_t)chunk * 3072;
    const int tx = tid & 15, ty = tid >> 4;
    float acc[8][8] = {};
    for (int k0 = 0; k0 < 3072; k0 += 8) {
        {
            int m = tid >> 1;
            int kb = (tid & 1) << 2;
            int r = bm + m;   // token row 0..255
            const float* ap = hid + (size_t)(l * 256 + r) * 24576 + inner0 + k0 + kb;
#pragma unroll
            for (int i = 0; i < 4; i++) As[kb + i][m] = ap[i];
        }
        {
            int kk = tid >> 5;
            int nb = (tid & 31) << 2;
            const float* bp = W1 + (kg0 + k0 + kk) * 512 + bn + nb;
#pragma unroll
            for (int i = 0; i < 4; i++) Bs[kk][nb + i] = bp[i];
        }
        __syncthreads();
#pragma unroll
        for (int k = 0; k < 8; k++) {
            float a[8], b[8];
#pragma unroll
            for (int i = 0; i < 8; i++) a[i] = As[k][ty * 8 + i];
#pragma unroll
            for (int j = 0; j < 8; j++) b[j] = Bs[k][tx * 8 + j];
#pragma unroll
            for (int i = 0; i < 8; i++)
#pragma unroll
                for (int j = 0; j < 8; j++)
                    acc[i][j] = fmaf(a[i], b[j], acc[i][j]);
        }
        __syncthreads();
    }
    float* outp = partial + (size_t)chunk * (256 * 512);
#pragma unroll
    for (int i = 0; i < 8; i++)
#pragma unroll
        for (int j = 0; j < 8; j++)
            outp[(size_t)(bm + ty * 8 + i) * 512 + bn + tx * 8 + j] = acc[i][j];
}

// reduce 32 split-K partials, +bias, relu -> h1 (256x512)
__global__ __launch_bounds__(256) void h1_reduce_kernel(
    const float* __restrict__ partial, const float* __restrict__ b1,
    float* __restrict__ h1)
{
    int idx = blockIdx.x * 256 + threadIdx.x;   // 0..131071
    float s = b1[idx & 511];
#pragma unroll
    for (int c = 0; c < 32; c++) s += partial[(size_t)c * 131072 + idx];
    h1[idx] = fmaxf(s, 0.f);
}

// ---------------------------------------------------------------------------
extern "C" void kernel_launch(void* const* d_in, const int* in_sizes, int n_in,
                              void* d_out, int out_size, void* d_ws, size_t ws_size,
                              hipStream_t stream)
{
    const int*   ids        = (const int*)d_in[0];
    const float* embed      = (const float*)d_in[1];
    const float* norm_f     = (const float*)d_in[2];
    const float* norm_w     = (const float*)d_in[3];
    const float* in_proj_w  = (const float*)d_in[4];
    const float* conv_w     = (const float*)d_in[5];
    const float* conv_b     = (const float*)d_in[6];
    const float* x_proj_w   = (const float*)d_in[7];
    const float* dt_w       = (const float*)d_in[8];
    const float* dt_b       = (const float*)d_in[9];
    const float* A_log      = (const float*)d_in[10];
    const float* Dp         = (const float*)d_in[11];
    const float* out_proj_w = (const float*)d_in[12];
    const float* ro_w1      = (const float*)d_in[13];
    const float* ro_b1      = (const float*)d_in[14];
    const float* ro_w2      = (const float*)d_in[15];
    const float* ro_b2      = (const float*)d_in[16];
    const float* ro_w3      = (const float*)d_in[17];
    const float* ro_b3      = (const float*)d_in[18];

    float* out         = (float*)d_out;
    float* main_logits = out;                              // 256*50280
    float* ro_logits   = out + (size_t)256 * 50280;        // 256*50280
    float* hid         = ro_logits + (size_t)256 * 50280;  // 4*256*24576

    float* w = (float*)d_ws;
    float* x       = w; w += 256 * 768;
    float* xn      = w; w += 256 * 768;
    float* xz      = w; w += 256 * 3072;
    float* xconv   = w; w += 256 * 1536;
    float* dbc     = w; w += 256 * 80;
    float* delta   = w; w += 256 * 1536;
    float* yb      = w; w += 256 * 1536;
    float* xf      = w; w += 256 * 768;
    float* h1      = w; w += 256 * 512;
    float* h2      = w; w += 256 * 256;
    float* partial = w; w += (size_t)32 * 256 * 512;       // split-K partials

    dim3 blk(256);

    gather_kernel<<<256, blk, 0, stream>>>(ids, embed, x);

    for (int l = 0; l < 4; l++) {
        rmsnorm_kernel<<<256, blk, 0, stream>>>(x, norm_w + l * 768, xn);
        // xz = xn @ in_proj_w[l]  (256x3072, K=768)
        gemm64_kernel<0, 0><<<dim3(48, 4), blk, 0, stream>>>(
            xn, in_proj_w + (size_t)l * 768 * 3072, nullptr, xz,
            256, 3072, 768, 768, 3072, 3072);
        conv_silu_kernel<<<256, blk, 0, stream>>>(
            xz, conv_w + l * 1536 * 4, conv_b + l * 1536, xconv);
        // dbc = xconv @ x_proj_w[l]  (256x80, K=1536)
        gemm64_kernel<0, 0><<<dim3(2, 4), blk, 0, stream>>>(
            xconv, x_proj_w + (size_t)l * 1536 * 80, nullptr, dbc,
            256, 80, 1536, 1536, 80, 80);
        // delta = softplus(dbc[:, :48] @ dt_w[l] + dt_b[l])  (256x1536, K=48)
        gemm64_kernel<0, 3><<<dim3(24, 4), blk, 0, stream>>>(
            dbc, dt_w + (size_t)l * 48 * 1536, dt_b + l * 1536, delta,
            256, 1536, 48, 80, 1536, 1536);
        scan_kernel<<<192, blk, 0, stream>>>(
            delta, xconv, dbc, xz, A_log + l * 1536 * 16, Dp + l * 1536,
            hid + (size_t)l * 256 * 24576, yb);
        // x += yb @ out_proj_w[l]  (256x768, K=1536), accumulate epilogue
        gemm64_kernel<0, 4><<<dim3(12, 4), blk, 0, stream>>>(
            yb, out_proj_w + (size_t)l * 1536 * 768, nullptr, x,
            256, 768, 1536, 1536, 768, 768);
    }

    rmsnorm_kernel<<<256, blk, 0, stream>>>(x, norm_f, xf);

    // main_logits = xf @ embed^T  (256x50280, K=768)
    gemm128_kernel<1, 0><<<dim3(393, 2), blk, 0, stream>>>(
        xf, embed, nullptr, main_logits, 256, 50280, 768, 768, 768, 50280);

    // readout MLP
    feat_splitk_kernel<<<dim3(4, 2, 32), blk, 0, stream>>>(hid, ro_w1, partial);
    h1_reduce_kernel<<<512, blk, 0, stream>>>(partial, ro_b1, h1);
    // h2 = relu(h1 @ ro_w2 + b2)  (256x256, K=512)
    gemm64_kernel<0, 2><<<dim3(4, 4), blk, 0, stream>>>(
        h1, ro_w2, ro_b2, h2, 256, 256, 512, 512, 256, 256);
    // readout_logits = h2 @ ro_w3 + b3  (256x50280, K=256)
    gemm128_kernel<0, 1><<<dim3(393, 2), blk, 0, stream>>>(
        h2, ro_w3, ro_b3, ro_logits, 256, 50280, 256, 256, 50280, 50280);
}

// Round 2
// 2488.806 us; speedup vs baseline: 1.5823x; 1.5823x over previous
//
#include <hip/hip_runtime.h>
#include <cmath>

typedef __attribute__((ext_vector_type(4))) float f32x4;
typedef __attribute__((ext_vector_type(8))) short s16x8;
typedef __attribute__((ext_vector_type(4))) short s16x4;

__device__ __forceinline__ float silu_f(float x) { return x / (1.f + expf(-x)); }

// fp32 -> bf16 round-to-nearest-even
__device__ __forceinline__ short f2bf(float f) {
    unsigned u = __float_as_uint(f);
    u += 0x7FFFu + ((u >> 16) & 1u);
    return (short)(u >> 16);
}

// ---------------------------------------------------------------------------
// gather: x[t,:] = embed[ids[t],:]
// ---------------------------------------------------------------------------
__global__ __launch_bounds__(256) void gather_kernel(
    const int* __restrict__ ids, const float* __restrict__ embed,
    float* __restrict__ x)
{
    int t = blockIdx.x, tid = threadIdx.x;
    int id = ids[t];
#pragma unroll
    for (int i = 0; i < 3; i++)
        x[t * 768 + i * 256 + tid] = embed[(size_t)id * 768 + i * 256 + tid];
}

// ---------------------------------------------------------------------------
// rmsnorm over DM=768, one block per token, 256 threads
// ---------------------------------------------------------------------------
__global__ __launch_bounds__(256) void rmsnorm_kernel(
    const float* __restrict__ x, const float* __restrict__ w,
    float* __restrict__ out)
{
    int t = blockIdx.x;
    int tid = threadIdx.x;
    float v0 = x[t * 768 + tid];
    float v1 = x[t * 768 + 256 + tid];
    float v2 = x[t * 768 + 512 + tid];
    float s = v0 * v0 + v1 * v1 + v2 * v2;
#pragma unroll
    for (int off = 32; off >= 1; off >>= 1) s += __shfl_xor(s, off, 64);
    __shared__ float red[4];
    int wid = tid >> 6, lane = tid & 63;
    if (lane == 0) red[wid] = s;
    __syncthreads();
    s = red[0] + red[1] + red[2] + red[3];
    float scale = rsqrtf(s * (1.f / 768.f) + 1e-5f);
    out[t * 768 + tid]       = v0 * scale * w[tid];
    out[t * 768 + 256 + tid] = v1 * scale * w[256 + tid];
    out[t * 768 + 512 + tid] = v2 * scale * w[512 + tid];
}

// ---------------------------------------------------------------------------
// fp32 GEMM, 64x64 tile, TK=16 (kept for small/precision-sensitive GEMMs)
// BT: 0 -> Bw is K x N row-major. EPI: 0 none, 2 relu(+bias), 3 softplus(+bias)
// ---------------------------------------------------------------------------
template <int BT, int EPI>
__global__ __launch_bounds__(256) void gemm64_kernel(
    const float* __restrict__ A, const float* __restrict__ Bw,
    const float* __restrict__ bias, float* __restrict__ C,
    int M, int N, int K, int lda, int ldb, int ldc)
{
    __shared__ float As[16][68];
    __shared__ float Bs[16][68];
    const int tid = threadIdx.x;
    const int bm = blockIdx.y * 64;
    const int bn = blockIdx.x * 64;
    const int tx = tid & 15, ty = tid >> 4;
    float acc[4][4] = {};
    for (int k0 = 0; k0 < K; k0 += 16) {
        {
            int m = tid >> 2;
            int kb = (tid & 3) << 2;
            bool mok = (bm + m) < M;
            const float* ap = A + (size_t)(bm + m) * lda + k0 + kb;
#pragma unroll
            for (int i = 0; i < 4; i++)
                As[kb + i][m] = (mok && (k0 + kb + i) < K) ? ap[i] : 0.f;
        }
        {
            int kk = tid >> 4;
            int nb = (tid & 15) << 2;
            bool kok = (k0 + kk) < K;
            const float* bp = Bw + (size_t)(k0 + kk) * ldb + bn + nb;
#pragma unroll
            for (int i = 0; i < 4; i++)
                Bs[kk][nb + i] = (kok && (bn + nb + i) < N) ? bp[i] : 0.f;
        }
        __syncthreads();
#pragma unroll
        for (int k = 0; k < 16; k++) {
            float a[4], b[4];
#pragma unroll
            for (int i = 0; i < 4; i++) a[i] = As[k][ty * 4 + i];
#pragma unroll
            for (int j = 0; j < 4; j++) b[j] = Bs[k][tx * 4 + j];
#pragma unroll
            for (int i = 0; i < 4; i++)
#pragma unroll
                for (int j = 0; j < 4; j++)
                    acc[i][j] = fmaf(a[i], b[j], acc[i][j]);
        }
        __syncthreads();
    }
#pragma unroll
    for (int i = 0; i < 4; i++) {
        int m = bm + ty * 4 + i;
        if (m >= M) continue;
#pragma unroll
        for (int j = 0; j < 4; j++) {
            int n = bn + tx * 4 + j;
            if (n >= N) continue;
            float v = acc[i][j];
            if (EPI >= 1 && EPI <= 3) v += bias[n];
            if (EPI == 2) v = fmaxf(v, 0.f);
            if (EPI == 3) v = fmaxf(v, 0.f) + log1pf(expf(-fabsf(v)));
            C[(size_t)m * ldc + n] = v;
        }
    }
}

// ---------------------------------------------------------------------------
// bf16 MFMA GEMM, 128x128 tile, BK=32, 4 waves each computing 64x64.
// fp32 inputs converted to bf16 inline during LDS staging.
// M is always 256 (multiple of 128); K must be a multiple of 32.
// BT: 0 -> Bw is K x N row-major; 1 -> Bw is N x K row-major (C = A*Bw^T).
// EPI: 0 none, 1 +bias, 4 C += v (accumulate).
// LDS tiles stored [row][k] with row stride 40 shorts (16B-aligned b128 reads,
// 2-way bank aliasing only).
// ---------------------------------------------------------------------------
template <int BT, int EPI>
__global__ __launch_bounds__(256) void mfma_gemm_kernel(
    const float* __restrict__ A, const float* __restrict__ Bw,
    const float* __restrict__ bias, float* __restrict__ C,
    int N, int K, int lda, int ldb, int ldc)
{
    __shared__ alignas(16) short As[128 * 40];
    __shared__ alignas(16) short Bs[128 * 40];
    const int tid = threadIdx.x;
    const int bm = blockIdx.y * 128;
    const int bn = blockIdx.x * 128;
    const int wave = tid >> 6, lane = tid & 63;
    const int quad = lane >> 4, lm = lane & 15;
    const int wm = (wave >> 1) * 64, wn = (wave & 1) * 64;
    const bool nfull = (bn + 128 <= N);
    const int arow = tid >> 1, akseg = (tid & 1) * 16;   // A/BT=1 staging
    const int kblk = (tid & 7) * 4, nblk = (tid >> 3) * 4; // BT=0 staging

    f32x4 acc[4][4] = {};

    for (int k0 = 0; k0 < K; k0 += 32) {
        // ---- A tile stage: 128 rows x 32 k ----
        {
            const float* ap = A + (size_t)(bm + arow) * lda + k0 + akseg;
            f32x4 v0 = *(const f32x4*)(ap);
            f32x4 v1 = *(const f32x4*)(ap + 4);
            f32x4 v2 = *(const f32x4*)(ap + 8);
            f32x4 v3 = *(const f32x4*)(ap + 12);
            s16x8 p0, p1;
            p0[0]=f2bf(v0[0]); p0[1]=f2bf(v0[1]); p0[2]=f2bf(v0[2]); p0[3]=f2bf(v0[3]);
            p0[4]=f2bf(v1[0]); p0[5]=f2bf(v1[1]); p0[6]=f2bf(v1[2]); p0[7]=f2bf(v1[3]);
            p1[0]=f2bf(v2[0]); p1[1]=f2bf(v2[1]); p1[2]=f2bf(v2[2]); p1[3]=f2bf(v2[3]);
            p1[4]=f2bf(v3[0]); p1[5]=f2bf(v3[1]); p1[6]=f2bf(v3[2]); p1[7]=f2bf(v3[3]);
            *(s16x8*)(&As[arow * 40 + akseg])     = p0;
            *(s16x8*)(&As[arow * 40 + akseg + 8]) = p1;
        }
        // ---- B tile stage: LDS layout [n][k] ----
        if (BT) {
            // Bw is N x K: row n maps directly
            if (nfull || (bn + arow) < N) {
                const float* bp = Bw + (size_t)(bn + arow) * ldb + k0 + akseg;
                f32x4 v0 = *(const f32x4*)(bp);
                f32x4 v1 = *(const f32x4*)(bp + 4);
                f32x4 v2 = *(const f32x4*)(bp + 8);
                f32x4 v3 = *(const f32x4*)(bp + 12);
                s16x8 p0, p1;
                p0[0]=f2bf(v0[0]); p0[1]=f2bf(v0[1]); p0[2]=f2bf(v0[2]); p0[3]=f2bf(v0[3]);
                p0[4]=f2bf(v1[0]); p0[5]=f2bf(v1[1]); p0[6]=f2bf(v1[2]); p0[7]=f2bf(v1[3]);
                p1[0]=f2bf(v2[0]); p1[1]=f2bf(v2[1]); p1[2]=f2bf(v2[2]); p1[3]=f2bf(v2[3]);
                p1[4]=f2bf(v3[0]); p1[5]=f2bf(v3[1]); p1[6]=f2bf(v3[2]); p1[7]=f2bf(v3[3]);
                *(s16x8*)(&Bs[arow * 40 + akseg])     = p0;
                *(s16x8*)(&Bs[arow * 40 + akseg + 8]) = p1;
            }
            // rows n >= N: stale LDS only feeds D columns we never store
        } else {
            // Bw is K x N: transpose 4x4 micro-tile in registers
            f32x4 r[4];
            if (nfull) {
#pragma unroll
                for (int i = 0; i < 4; i++)
                    r[i] = *(const f32x4*)(Bw + (size_t)(k0 + kblk + i) * ldb + bn + nblk);
            } else {
#pragma unroll
                for (int i = 0; i < 4; i++)
#pragma unroll
                    for (int j = 0; j < 4; j++) {
                        int col = bn + nblk + j;
                        r[i][j] = (col < N) ? Bw[(size_t)(k0 + kblk + i) * ldb + col] : 0.f;
                    }
            }
#pragma unroll
            for (int j = 0; j < 4; j++) {
                s16x4 q;
                q[0] = f2bf(r[0][j]); q[1] = f2bf(r[1][j]);
                q[2] = f2bf(r[2][j]); q[3] = f2bf(r[3][j]);
                *(s16x4*)(&Bs[(nblk + j) * 40 + kblk]) = q;
            }
        }
        __syncthreads();
        // ---- MFMA pass ----
        s16x8 af[4], bf_[4];
#pragma unroll
        for (int i = 0; i < 4; i++)
            af[i] = *(const s16x8*)(&As[(wm + i * 16 + lm) * 40 + quad * 8]);
#pragma unroll
        for (int j = 0; j < 4; j++)
            bf_[j] = *(const s16x8*)(&Bs[(wn + j * 16 + lm) * 40 + quad * 8]);
#pragma unroll
        for (int i = 0; i < 4; i++)
#pragma unroll
            for (int j = 0; j < 4; j++)
                acc[i][j] = __builtin_amdgcn_mfma_f32_16x16x32_bf16(
                    af[i], bf_[j], acc[i][j], 0, 0, 0);
        __syncthreads();
    }
    // ---- epilogue: C/D layout col=lane&15, row=quad*4+reg ----
#pragma unroll
    for (int i = 0; i < 4; i++) {
#pragma unroll
        for (int j = 0; j < 4; j++) {
            int col = bn + wn + j * 16 + lm;
            if (col >= N) continue;
#pragma unroll
            for (int r = 0; r < 4; r++) {
                int row = bm + wm + i * 16 + quad * 4 + r;
                float v = acc[i][j][r];
                if (EPI == 1) v += bias[col];
                float* cp = &C[(size_t)row * ldc + col];
                if (EPI == 4) v += *cp;
                *cp = v;
            }
        }
    }
}

// ---------------------------------------------------------------------------
// causal depthwise conv (DC=4) + silu. One block per token row.
// ---------------------------------------------------------------------------
__global__ __launch_bounds__(256) void conv_silu_kernel(
    const float* __restrict__ xz, const float* __restrict__ cw,
    const float* __restrict__ cb, float* __restrict__ xconv)
{
    int row = blockIdx.x;       // b*128 + t
    int t = row & 127;
    int tid = threadIdx.x;
    for (int c = tid; c < 1536; c += 256) {
        float acc = cb[c];
#pragma unroll
        for (int k = 0; k < 4; k++) {
            int tt = t - 3 + k;
            if (tt >= 0) acc += cw[c * 4 + k] * xz[(size_t)(row - 3 + k) * 3072 + c];
        }
        xconv[(size_t)row * 1536 + c] = silu_f(acc);
    }
}

// ---------------------------------------------------------------------------
// selective scan: one lane per (b, di, ds); 16-lane shuffle reduce for y.
// ---------------------------------------------------------------------------
__global__ __launch_bounds__(256) void scan_kernel(
    const float* __restrict__ delta, const float* __restrict__ xconv,
    const float* __restrict__ dbc, const float* __restrict__ xz,
    const float* __restrict__ A_log, const float* __restrict__ Dp,
    float* __restrict__ hid_l, float* __restrict__ yout)
{
    int gtid = blockIdx.x * 256 + threadIdx.x;  // 0..49151 = B*DI*DS
    int ds = gtid & 15;
    int di = (gtid >> 4) % 1536;
    int b  = gtid / 24576;
    float a = -expf(A_log[di * 16 + ds]);
    float dval = Dp[di];
    float h = 0.f;
    for (int t = 0; t < 128; t++) {
        int row = b * 128 + t;
        float dlt = delta[row * 1536 + di];
        float u   = xconv[row * 1536 + di];
        float Bv  = dbc[row * 80 + 48 + ds];
        float Cv  = dbc[row * 80 + 64 + ds];
        h = expf(dlt * a) * h + dlt * Bv * u;
        hid_l[(size_t)row * 24576 + di * 16 + ds] = h;
        float p = h * Cv;
        p += __shfl_xor(p, 1, 64);
        p += __shfl_xor(p, 2, 64);
        p += __shfl_xor(p, 4, 64);
        p += __shfl_xor(p, 8, 64);
        if (ds == 0) {
            float z = xz[(size_t)row * 3072 + 1536 + di];
            yout[row * 1536 + di] = (p + dval * u) * silu_f(z);
        }
    }
}

// ---------------------------------------------------------------------------
// readout GEMM1 split-K, bf16 MFMA: feat(256 x 98304) @ ro_w1(98304 x 512).
// 64 chunks of K=1536 (each inside one layer slab). grid (4, 2, 64).
// ---------------------------------------------------------------------------
__global__ __launch_bounds__(256) void feat_splitk_mfma_kernel(
    const float* __restrict__ hid, const float* __restrict__ W1,
    float* __restrict__ partial)
{
    __shared__ alignas(16) short As[128 * 40];
    __shared__ alignas(16) short Bs[128 * 40];
    const int tid = threadIdx.x;
    const int bn = blockIdx.x * 128;
    const int bm = blockIdx.y * 128;
    const int chunk = blockIdx.z;
    const int l = chunk >> 4;                 // 16 chunks per layer slab
    const int inner0 = (chunk & 15) * 1536;
    const size_t kg0 = (size_t)chunk * 1536;
    const int wave = tid >> 6, lane = tid & 63;
    const int quad = lane >> 4, lm = lane & 15;
    const int wm = (wave >> 1) * 64, wn = (wave & 1) * 64;
    const int arow = tid >> 1, akseg = (tid & 1) * 16;
    const int kblk = (tid & 7) * 4, nblk = (tid >> 3) * 4;

    f32x4 acc[4][4] = {};

    for (int k0 = 0; k0 < 1536; k0 += 32) {
        {
            const float* ap = hid + (size_t)(l * 256 + bm + arow) * 24576 + inner0 + k0 + akseg;
            f32x4 v0 = *(const f32x4*)(ap);
            f32x4 v1 = *(const f32x4*)(ap + 4);
            f32x4 v2 = *(const f32x4*)(ap + 8);
            f32x4 v3 = *(const f32x4*)(ap + 12);
            s16x8 p0, p1;
            p0[0]=f2bf(v0[0]); p0[1]=f2bf(v0[1]); p0[2]=f2bf(v0[2]); p0[3]=f2bf(v0[3]);
            p0[4]=f2bf(v1[0]); p0[5]=f2bf(v1[1]); p0[6]=f2bf(v1[2]); p0[7]=f2bf(v1[3]);
            p1[0]=f2bf(v2[0]); p1[1]=f2bf(v2[1]); p1[2]=f2bf(v2[2]); p1[3]=f2bf(v2[3]);
            p1[4]=f2bf(v3[0]); p1[5]=f2bf(v3[1]); p1[6]=f2bf(v3[2]); p1[7]=f2bf(v3[3]);
            *(s16x8*)(&As[arow * 40 + akseg])     = p0;
            *(s16x8*)(&As[arow * 40 + akseg + 8]) = p1;
        }
        {
            f32x4 r[4];
#pragma unroll
            for (int i = 0; i < 4; i++)
                r[i] = *(const f32x4*)(W1 + (kg0 + k0 + kblk + i) * 512 + bn + nblk);
#pragma unroll
            for (int j = 0; j < 4; j++) {
                s16x4 q;
                q[0] = f2bf(r[0][j]); q[1] = f2bf(r[1][j]);
                q[2] = f2bf(r[2][j]); q[3] = f2bf(r[3][j]);
                *(s16x4*)(&Bs[(nblk + j) * 40 + kblk]) = q;
            }
        }
        __syncthreads();
        s16x8 af[4], bf_[4];
#pragma unroll
        for (int i = 0; i < 4; i++)
            af[i] = *(const s16x8*)(&As[(wm + i * 16 + lm) * 40 + quad * 8]);
#pragma unroll
        for (int j = 0; j < 4; j++)
            bf_[j] = *(const s16x8*)(&Bs[(wn + j * 16 + lm) * 40 + quad * 8]);
#pragma unroll
        for (int i = 0; i < 4; i++)
#pragma unroll
            for (int j = 0; j < 4; j++)
                acc[i][j] = __builtin_amdgcn_mfma_f32_16x16x32_bf16(
                    af[i], bf_[j], acc[i][j], 0, 0, 0);
        __syncthreads();
    }
    float* outp = partial + (size_t)chunk * (256 * 512);
#pragma unroll
    for (int i = 0; i < 4; i++)
#pragma unroll
        for (int j = 0; j < 4; j++) {
            int col = bn + wn + j * 16 + lm;
#pragma unroll
            for (int r = 0; r < 4; r++) {
                int row = bm + wm + i * 16 + quad * 4 + r;
                outp[(size_t)row * 512 + col] = acc[i][j][r];
            }
        }
}

// reduce 64 split-K partials, +bias, relu -> h1 (256x512)
__global__ __launch_bounds__(256) void h1_reduce_kernel(
    const float* __restrict__ partial, const float* __restrict__ b1,
    float* __restrict__ h1)
{
    int idx = blockIdx.x * 256 + threadIdx.x;   // 0..131071
    float s = b1[idx & 511];
#pragma unroll
    for (int c = 0; c < 64; c++) s += partial[(size_t)c * 131072 + idx];
    h1[idx] = fmaxf(s, 0.f);
}

// ---------------------------------------------------------------------------
extern "C" void kernel_launch(void* const* d_in, const int* in_sizes, int n_in,
                              void* d_out, int out_size, void* d_ws, size_t ws_size,
                              hipStream_t stream)
{
    const int*   ids        = (const int*)d_in[0];
    const float* embed      = (const float*)d_in[1];
    const float* norm_f     = (const float*)d_in[2];
    const float* norm_w     = (const float*)d_in[3];
    const float* in_proj_w  = (const float*)d_in[4];
    const float* conv_w     = (const float*)d_in[5];
    const float* conv_b     = (const float*)d_in[6];
    const float* x_proj_w   = (const float*)d_in[7];
    const float* dt_w       = (const float*)d_in[8];
    const float* dt_b       = (const float*)d_in[9];
    const float* A_log      = (const float*)d_in[10];
    const float* Dp         = (const float*)d_in[11];
    const float* out_proj_w = (const float*)d_in[12];
    const float* ro_w1      = (const float*)d_in[13];
    const float* ro_b1      = (const float*)d_in[14];
    const float* ro_w2      = (const float*)d_in[15];
    const float* ro_b2      = (const float*)d_in[16];
    const float* ro_w3      = (const float*)d_in[17];
    const float* ro_b3      = (const float*)d_in[18];

    float* out         = (float*)d_out;
    float* main_logits = out;                              // 256*50280
    float* ro_logits   = out + (size_t)256 * 50280;        // 256*50280
    float* hid         = ro_logits + (size_t)256 * 50280;  // 4*256*24576

    float* w = (float*)d_ws;
    float* x       = w; w += 256 * 768;
    float* xn      = w; w += 256 * 768;
    float* xz      = w; w += 256 * 3072;
    float* xconv   = w; w += 256 * 1536;
    float* dbc     = w; w += 256 * 80;
    float* delta   = w; w += 256 * 1536;
    float* yb      = w; w += 256 * 1536;
    float* xf      = w; w += 256 * 768;
    float* h1      = w; w += 256 * 512;
    float* h2      = w; w += 256 * 256;
    float* partial = w; w += (size_t)64 * 256 * 512;       // split-K partials

    dim3 blk(256);

    gather_kernel<<<256, blk, 0, stream>>>(ids, embed, x);

    for (int l = 0; l < 4; l++) {
        rmsnorm_kernel<<<256, blk, 0, stream>>>(x, norm_w + l * 768, xn);
        // xz = xn @ in_proj_w[l]  (256x3072, K=768)  [bf16 MFMA]
        mfma_gemm_kernel<0, 0><<<dim3(24, 2), blk, 0, stream>>>(
            xn, in_proj_w + (size_t)l * 768 * 3072, nullptr, xz,
            3072, 768, 768, 3072, 3072);
        conv_silu_kernel<<<256, blk, 0, stream>>>(
            xz, conv_w + l * 1536 * 4, conv_b + l * 1536, xconv);
        // dbc = xconv @ x_proj_w[l]  (256x80, K=1536)  [fp32 — feeds scan]
        gemm64_kernel<0, 0><<<dim3(2, 4), blk, 0, stream>>>(
            xconv, x_proj_w + (size_t)l * 1536 * 80, nullptr, dbc,
            256, 80, 1536, 1536, 80, 80);
        // delta = softplus(dbc[:, :48] @ dt_w[l] + dt_b[l])  [fp32]
        gemm64_kernel<0, 3><<<dim3(24, 4), blk, 0, stream>>>(
            dbc, dt_w + (size_t)l * 48 * 1536, dt_b + l * 1536, delta,
            256, 1536, 48, 80, 1536, 1536);
        scan_kernel<<<192, blk, 0, stream>>>(
            delta, xconv, dbc, xz, A_log + l * 1536 * 16, Dp + l * 1536,
            hid + (size_t)l * 256 * 24576, yb);
        // x += yb @ out_proj_w[l]  (256x768, K=1536)  [bf16 MFMA, accumulate]
        mfma_gemm_kernel<0, 4><<<dim3(6, 2), blk, 0, stream>>>(
            yb, out_proj_w + (size_t)l * 1536 * 768, nullptr, x,
            768, 1536, 1536, 768, 768);
    }

    rmsnorm_kernel<<<256, blk, 0, stream>>>(x, norm_f, xf);

    // main_logits = xf @ embed^T  (256x50280, K=768)  [bf16 MFMA, BT=1]
    mfma_gemm_kernel<1, 0><<<dim3(393, 2), blk, 0, stream>>>(
        xf, embed, nullptr, main_logits, 50280, 768, 768, 768, 50280);

    // readout MLP
    feat_splitk_mfma_kernel<<<dim3(4, 2, 64), blk, 0, stream>>>(hid, ro_w1, partial);
    h1_reduce_kernel<<<512, blk, 0, stream>>>(partial, ro_b1, h1);
    // h2 = relu(h1 @ ro_w2 + b2)  (256x256, K=512)  [fp32, tiny]
    gemm64_kernel<0, 2><<<dim3(4, 4), blk, 0, stream>>>(
        h1, ro_w2, ro_b2, h2, 256, 256, 512, 512, 256, 256);
    // readout_logits = h2 @ ro_w3 + b3  (256x50280, K=256)  [bf16 MFMA]
    mfma_gemm_kernel<0, 1><<<dim3(393, 2), blk, 0, stream>>>(
        h2, ro_w3, ro_b3, ro_logits, 50280, 256, 256, 50280, 50280);
}